// Round 2
// baseline (2060.360 us; speedup 1.0000x reference)
//
#include <hip/hip_runtime.h>
#include <math.h>

#define EPS 1e-6f
#define NWG 256

// ws float layout:
//   h    @ 0      [2][1024]
//   qkv  @ 2048   5 x [2][3072]   (z: q|k|v blocks of 1024)
//   ao   @ 32768  5 x [2][1024]
//   gu   @ 43008  5 x [2][2][4096]  (s, gate/up, f)
//   cnt  @ 126976 (unsigned barrier counter)
#define WS_H    0
#define WS_QKV  2048
#define WS_AO   32768
#define WS_GU   43008
#define WS_CNT  126976

// ---------------- init: zero accumulators + barrier + build h ----------------
__global__ void init_kernel(const float* __restrict__ past_hidden,
                            const float* __restrict__ codec_emb,
                            const int* __restrict__ tok,
                            float* __restrict__ ws,
                            float* __restrict__ logits)
{
    int idx = blockIdx.x * blockDim.x + threadIdx.x;
    int stride = gridDim.x * blockDim.x;
    for (int i = idx; i < 30720; i += stride) ws[WS_QKV + i] = 0.f;
    for (int i = idx; i < 10240; i += stride) ws[WS_AO + i] = 0.f;
    for (int i = idx; i < 81920; i += stride) ws[WS_GU + i] = 0.f;
    for (int i = idx; i < 30720; i += stride) logits[i] = 0.f;
    for (int i = idx; i < 64; i += stride) ((unsigned*)(ws + WS_CNT))[i] = 0u;
    int t = tok[0];
    for (int i = idx; i < 1024; i += stride) {
        ws[i]        = past_hidden[i];
        ws[1024 + i] = codec_emb[(size_t)t * 1024 + i];
    }
}

// ---------------- grid barrier (device-scope, monotonic counter) ----------------
__device__ __forceinline__ void gbar(unsigned* cnt, unsigned target)
{
    __threadfence();   // release: flush our writes past non-coherent L2
    __syncthreads();   // also drains vmcnt/lgkmcnt for the whole block
    if (threadIdx.x == 0) {
        __hip_atomic_fetch_add(cnt, 1u, __ATOMIC_ACQ_REL, __HIP_MEMORY_SCOPE_AGENT);
        while (__hip_atomic_load(cnt, __ATOMIC_RELAXED, __HIP_MEMORY_SCOPE_AGENT) < target) {
            __builtin_amdgcn_s_sleep(2);
        }
    }
    __syncthreads();
    __threadfence();   // acquire: invalidate stale L1/L2 lines
}

__device__ __forceinline__ float wave_red64(float v)
{
    for (int o = 32; o >= 1; o >>= 1) v += __shfl_down(v, o, 64);
    return v;
}

// ---------------- rmsnorm prologues (redundant per WG; h is L2/L3-hot) ----------------
__device__ __forceinline__ void load_rms2(const float* __restrict__ h,
                                          const float* __restrict__ nw,
                                          float* __restrict__ x0, float* __restrict__ x1,
                                          float* __restrict__ red)
{
    int t = threadIdx.x;
    float ss0 = 0.f, ss1 = 0.f;
    for (int d = t; d < 1024; d += 256) {
        float v0 = h[d], v1 = h[1024 + d];
        x0[d] = v0; x1[d] = v1;
        ss0 += v0 * v0; ss1 += v1 * v1;
    }
    ss0 = wave_red64(ss0); ss1 = wave_red64(ss1);
    if ((t & 63) == 0) { red[t >> 6] = ss0; red[4 + (t >> 6)] = ss1; }
    __syncthreads();
    float s0 = red[0] + red[1] + red[2] + red[3];
    float s1 = red[4] + red[5] + red[6] + red[7];
    float sc0 = rsqrtf(s0 / 1024.f + EPS);
    float sc1 = rsqrtf(s1 / 1024.f + EPS);
    __syncthreads();
    for (int d = t; d < 1024; d += 256) {
        float w = nw[d];
        x0[d] *= sc0 * w; x1[d] *= sc1 * w;
    }
    __syncthreads();
}

__device__ __forceinline__ void load_rms1(const float* __restrict__ hrow,
                                          const float* __restrict__ nw,
                                          float* __restrict__ x,
                                          float* __restrict__ red)
{
    int t = threadIdx.x;
    float ss = 0.f;
    for (int d = t; d < 1024; d += 256) { float v = hrow[d]; x[d] = v; ss += v * v; }
    ss = wave_red64(ss);
    if ((t & 63) == 0) red[t >> 6] = ss;
    __syncthreads();
    float s = red[0] + red[1] + red[2] + red[3];
    float sc = rsqrtf(s / 1024.f + EPS);
    __syncthreads();
    for (int d = t; d < 1024; d += 256) x[d] *= sc * nw[d];
    __syncthreads();
}

// ---------------- one GEMV task: 256 cols x 64 K-rows, split-K atomic output ----------------
// Wt = W + kb*64*N + jb*256 ; x0/x1 point at the 64-row slice of x ; o0/o1 at out + jb*256
template <int S>
__device__ __forceinline__ void task_gemm(const float* __restrict__ x0,
                                          const float* __restrict__ x1,
                                          const float* __restrict__ Wt, int N,
                                          float* __restrict__ o0, float* __restrict__ o1,
                                          float* __restrict__ red)
{
    const int t = threadIdx.x, lane = t & 63, dp = t >> 6;
    const float* Wp = Wt + (size_t)(dp * 16) * N + lane * 4;
    const float* xa = x0 + dp * 16;
    const float* xb = (S == 2) ? (x1 + dp * 16) : nullptr;
    float a0 = 0.f, a1 = 0.f, a2 = 0.f, a3 = 0.f;
    float b0 = 0.f, b1 = 0.f, b2 = 0.f, b3 = 0.f;
#pragma unroll
    for (int i = 0; i < 16; ++i) {
        float4 w = *reinterpret_cast<const float4*>(Wp + (size_t)i * N);
        float xv = xa[i];
        a0 += xv * w.x; a1 += xv * w.y; a2 += xv * w.z; a3 += xv * w.w;
        if (S == 2) {
            float yv = xb[i];
            b0 += yv * w.x; b1 += yv * w.y; b2 += yv * w.z; b3 += yv * w.w;
        }
    }
    __syncthreads();   // protect red reuse (previous reads done)
    red[(dp * S + 0) * 256 + lane * 4 + 0] = a0;
    red[(dp * S + 0) * 256 + lane * 4 + 1] = a1;
    red[(dp * S + 0) * 256 + lane * 4 + 2] = a2;
    red[(dp * S + 0) * 256 + lane * 4 + 3] = a3;
    if (S == 2) {
        red[(dp * S + 1) * 256 + lane * 4 + 0] = b0;
        red[(dp * S + 1) * 256 + lane * 4 + 1] = b1;
        red[(dp * S + 1) * 256 + lane * 4 + 2] = b2;
        red[(dp * S + 1) * 256 + lane * 4 + 3] = b3;
    }
    __syncthreads();
    for (int o = t; o < S * 256; o += 256) {
        int s = o >> 8, col = o & 255;
        float sum = red[(0 * S + s) * 256 + col] + red[(1 * S + s) * 256 + col]
                  + red[(2 * S + s) * 256 + col] + red[(3 * S + s) * 256 + col];
        atomicAdd(((s == 0) ? o0 : o1) + col, sum);
    }
}

// touch-load a 256x64 tile into this CU's L2 (read-only prefetch)
__device__ __forceinline__ float touch_tile(const float* __restrict__ Wt, int N)
{
    const int t = threadIdx.x, lane = t & 63, dp = t >> 6;
    const float* Wp = Wt + (size_t)(dp * 16) * N + lane * 4;
    float s = 0.f;
#pragma unroll
    for (int i = 0; i < 16; ++i) {
        float4 w = *reinterpret_cast<const float4*>(Wp + (size_t)i * N);
        s += w.x + w.y + w.z + w.w;
    }
    return s;
}

// ---------------- attention for one head (blocks 0..7), 256 threads ----------------
__device__ void attn_head(const float* __restrict__ qkv,
                          const float* __restrict__ qnw, const float* __restrict__ knw,
                          float* __restrict__ ao, float* __restrict__ kvc,
                          int head, float* __restrict__ red)
{
    const int t = threadIdx.x;
    const int d = t & 127;
    const bool act = t < 128;
    float q0 = 0.f, q1 = 0.f, k0 = 0.f, k1 = 0.f, v0 = 0.f, v1 = 0.f, qw = 0.f, kw = 0.f;
    if (act) {
        q0 = qkv[head * 128 + d];           q1 = qkv[3072 + head * 128 + d];
        k0 = qkv[1024 + head * 128 + d];    k1 = qkv[3072 + 1024 + head * 128 + d];
        v0 = qkv[2048 + head * 128 + d];    v1 = qkv[3072 + 2048 + head * 128 + d];
        qw = qnw[d]; kw = knw[d];
    }
    auto bred = [&](float val) -> float {
        red[t] = act ? val : 0.f; __syncthreads();
        for (int off = 128; off >= 1; off >>= 1) {
            if (t < off) red[t] += red[t + off];
            __syncthreads();
        }
        float r = red[0]; __syncthreads();
        return r;
    };
    float qs0 = bred(q0 * q0), qs1 = bred(q1 * q1);
    float ks0 = bred(k0 * k0), ks1 = bred(k1 * k1);
    float qsc0 = rsqrtf(qs0 / 128.f + EPS), qsc1 = rsqrtf(qs1 / 128.f + EPS);
    float ksc0 = rsqrtf(ks0 / 128.f + EPS), ksc1 = rsqrtf(ks1 / 128.f + EPS);
    float* qb = red + 256;   // [s][128]
    float* kb = red + 512;
    if (act) {
        qb[d] = q0 * qsc0 * qw; qb[128 + d] = q1 * qsc1 * qw;
        kb[d] = k0 * ksc0 * kw; kb[128 + d] = k1 * ksc1 * kw;
    }
    __syncthreads();
    float qr0 = 0.f, qr1 = 0.f, kr0 = 0.f, kr1 = 0.f;
    if (act) {
        float invf = powf(10000.f, -(float)(d & 63) / 64.f);
        qr0 = qb[d];            // pos 0: angle 0
        kr0 = kb[d];
        float c = cosf(invf), si = sinf(invf);   // pos 1
        float qrot = (d < 64) ? -qb[128 + d + 64] : qb[128 + d - 64];
        float krot = (d < 64) ? -kb[128 + d + 64] : kb[128 + d - 64];
        qr1 = qb[128 + d] * c + qrot * si;
        kr1 = kb[128 + d] * c + krot * si;
        kvc[head * 256 + d]              = kr0;
        kvc[head * 256 + 128 + d]        = kr1;
        kvc[2048 + head * 256 + d]       = v0;
        kvc[2048 + head * 256 + 128 + d] = v1;
    }
    float p00 = bred(qr0 * kr0), p01 = bred(qr0 * kr1);
    float p10 = bred(qr1 * kr0), p11 = bred(qr1 * kr1);
    const float scale = 0.08838834764831845f;
    float s00 = p00 * scale, s01 = p01 * scale - 1e9f;
    float m0 = fmaxf(s00, s01);
    float e0 = expf(s00 - m0), e1 = expf(s01 - m0);
    float in0 = 1.f / (e0 + e1);
    float w00 = e0 * in0, w01 = e1 * in0;
    float s10 = p10 * scale, s11 = p11 * scale;
    float m1 = fmaxf(s10, s11);
    float f0 = expf(s10 - m1), f1 = expf(s11 - m1);
    float in1 = 1.f / (f0 + f1);
    float w10 = f0 * in1, w11 = f1 * in1;
    if (act) {
        atomicAdd(ao + head * 128 + d,        w00 * v0 + w01 * v1);
        atomicAdd(ao + 1024 + head * 128 + d, w10 * v0 + w11 * v1);
    }
}

// ---------------- the persistent mega-kernel ----------------
__global__ __launch_bounds__(256) void mega_kernel(
    const float* __restrict__ Wq, const float* __restrict__ Wk, const float* __restrict__ Wv,
    const float* __restrict__ Wo,
    const float* __restrict__ qnw_all, const float* __restrict__ knw_all,
    const float* __restrict__ ln1_all, const float* __restrict__ ln2_all,
    const float* __restrict__ Wg, const float* __restrict__ Wu, const float* __restrict__ Wd,
    const float* __restrict__ fnw, const float* __restrict__ lmh,
    float* __restrict__ ws, float* __restrict__ logits, float* __restrict__ kvc_all)
{
    __shared__ float xs0[1024];
    __shared__ float xs1[1024];
    __shared__ float red[2048];
    const int wg = blockIdx.x;
    unsigned* cnt = (unsigned*)(ws + WS_CNT);
    unsigned target = 0;
    float* h = ws + WS_H;
    float sink = 0.f;

    for (int l = 0; l < 5; ++l) {
        const float* wq_ = Wq + (size_t)l * 1048576;
        const float* wk_ = Wk + (size_t)l * 1048576;
        const float* wv_ = Wv + (size_t)l * 1048576;
        const float* wo_ = Wo + (size_t)l * 1048576;
        const float* wg_ = Wg + (size_t)l * 4194304;
        const float* wu_ = Wu + (size_t)l * 4194304;
        const float* wd_ = Wd + (size_t)l * 4194304;
        float* qkv = ws + WS_QKV + l * 6144;
        float* ao  = ws + WS_AO  + l * 2048;
        float* gu  = ws + WS_GU  + l * 16384;

        // ---- phase: QKV projection (192 tasks) ----
        load_rms2(h, ln1_all + l * 1024, xs0, xs1, red);
        if (wg < 192) {
            int z = wg >> 6, r = wg & 63, jb = r >> 4, kb = r & 15;
            const float* Wz = (z == 0) ? wq_ : ((z == 1) ? wk_ : wv_);
            task_gemm<2>(&xs0[kb * 64], &xs1[kb * 64],
                         Wz + (size_t)(kb * 64) * 1024 + jb * 256, 1024,
                         qkv + z * 1024 + jb * 256, qkv + 3072 + z * 1024 + jb * 256, red);
        }
        if (wg < 64) {            // prefetch my O tile
            int jb = wg >> 4, kb = wg & 15;
            sink += touch_tile(wo_ + (size_t)(kb * 64) * 1024 + jb * 256, 1024);
        } else {                  // prefetch my gate (GU round-1) tile
            int jb = wg >> 4, kb = wg & 15;
            sink += touch_tile(wg_ + (size_t)(kb * 64) * 4096 + jb * 256, 4096);
        }
        target += NWG; gbar(cnt, target);

        // ---- phase: attention (8 tasks) ----
        if (wg < 8)
            attn_head(qkv, qnw_all + l * 128, knw_all + l * 128, ao,
                      kvc_all + (size_t)(2 * l) * 2048, wg, red);
        if (wg < 64) {            // prefetch my gate tile (jb 0..3)
            int jb = wg >> 4, kb = wg & 15;
            sink += touch_tile(wg_ + (size_t)(kb * 64) * 4096 + jb * 256, 4096);
        }
        target += NWG; gbar(cnt, target);

        // ---- phase: O projection (64 tasks), residual into h ----
        {
            int t = threadIdx.x;
            for (int d2 = t; d2 < 1024; d2 += 256) { xs0[d2] = ao[d2]; xs1[d2] = ao[1024 + d2]; }
            __syncthreads();
        }
        if (wg < 64) {
            int jb = wg >> 4, kb = wg & 15;
            task_gemm<2>(&xs0[kb * 64], &xs1[kb * 64],
                         wo_ + (size_t)(kb * 64) * 1024 + jb * 256, 1024,
                         h + jb * 256, h + 1024 + jb * 256, red);
        }
        {                         // prefetch my up (GU round-2) tile
            int jb = wg >> 4, kb = wg & 15;
            sink += touch_tile(wu_ + (size_t)(kb * 64) * 4096 + jb * 256, 4096);
        }
        target += NWG; gbar(cnt, target);

        // ---- phase: gate+up (512 tasks, 2 rounds) ----
        load_rms2(h, ln2_all + l * 1024, xs0, xs1, red);
        {
            int jb = wg >> 4, kb = wg & 15;
            task_gemm<2>(&xs0[kb * 64], &xs1[kb * 64],
                         wg_ + (size_t)(kb * 64) * 4096 + jb * 256, 4096,
                         gu + jb * 256, gu + 8192 + jb * 256, red);
            task_gemm<2>(&xs0[kb * 64], &xs1[kb * 64],
                         wu_ + (size_t)(kb * 64) * 4096 + jb * 256, 4096,
                         gu + 4096 + jb * 256, gu + 8192 + 4096 + jb * 256, red);
            int jb2 = wg >> 6, kb2 = wg & 63;   // prefetch my down tile
            sink += touch_tile(wd_ + (size_t)(kb2 * 64) * 1024 + jb2 * 256, 1024);
        }
        target += NWG; gbar(cnt, target);

        // ---- phase: down proj (256 tasks), silu fused, residual into h ----
        {
            int jb = wg >> 6, kb = wg & 63;
            int t = threadIdx.x;
            if (t < 128) {
                int s = t >> 6, f = kb * 64 + (t & 63);
                float g = gu[s * 8192 + f];
                float u = gu[s * 8192 + 4096 + f];
                xs0[t & 63 + 0] = 0.f; // placeholder avoided below
            }
            __syncthreads();
            if (t < 128) {
                int s = t >> 6, f = kb * 64 + (t & 63);
                float g = gu[s * 8192 + f];
                float u = gu[s * 8192 + 4096 + f];
                float a = (g / (1.f + expf(-g))) * u;
                if (s == 0) xs0[t & 63] = a; else xs1[t & 63] = a;
            }
            __syncthreads();
            task_gemm<2>(&xs0[0], &xs1[0],
                         wd_ + (size_t)(kb * 64) * 1024 + jb * 256, 1024,
                         h + jb * 256, h + 1024 + jb * 256, red);
            if (l < 4) {          // prefetch next layer's QKV tile
                if (wg < 192) {
                    int z = wg >> 6, r = wg & 63, jb3 = r >> 4, kb3 = r & 15;
                    const float* nq = (z == 0) ? (Wq + (size_t)(l + 1) * 1048576)
                                   : ((z == 1) ? (Wk + (size_t)(l + 1) * 1048576)
                                               : (Wv + (size_t)(l + 1) * 1048576));
                    sink += touch_tile(nq + (size_t)(kb3 * 64) * 1024 + jb3 * 256, 1024);
                }
            } else {              // prefetch lm round-1 tile
                int n = wg >> 7, r = wg & 127, jb3 = r >> 4, kb3 = r & 15;
                sink += touch_tile(lmh + (size_t)n * 2097152 + (size_t)(kb3 * 64) * 2048 + jb3 * 256, 2048);
            }
        }
        target += NWG; gbar(cnt, target);
    }

    // ---- final norm + lm heads (1920 tasks) ----
    load_rms1(h + 1024, fnw, xs0, red);
    for (int task = wg; task < 1920; task += NWG) {
        int n = task >> 7, r = task & 127, jb = r >> 4, kb = r & 15;
        task_gemm<1>(&xs0[kb * 64], nullptr,
                     lmh + (size_t)n * 2097152 + (size_t)(kb * 64) * 2048 + jb * 256, 2048,
                     logits + n * 2048 + jb * 256, nullptr, red);
    }

    if (sink == -1.2345e38f) atomicAdd(h, 1.0f);   // keep touch loads alive
}

extern "C" void kernel_launch(void* const* d_in, const int* in_sizes, int n_in,
                              void* d_out, int out_size, void* d_ws, size_t ws_size,
                              hipStream_t stream)
{
    const float* past_hidden = (const float*)d_in[0];
    const int*   cb0         = (const int*)d_in[1];
    const float* codec_emb   = (const float*)d_in[2];
    const float* Wq  = (const float*)d_in[3];
    const float* Wk  = (const float*)d_in[4];
    const float* Wv  = (const float*)d_in[5];
    const float* Wo  = (const float*)d_in[6];
    const float* qnw = (const float*)d_in[7];
    const float* knw = (const float*)d_in[8];
    const float* ln1 = (const float*)d_in[9];
    const float* ln2 = (const float*)d_in[10];
    const float* Wg  = (const float*)d_in[11];
    const float* Wu  = (const float*)d_in[12];
    const float* Wd  = (const float*)d_in[13];
    const float* fnw = (const float*)d_in[14];
    const float* lmh = (const float*)d_in[15];

    float* out    = (float*)d_out;
    float* ws     = (float*)d_ws;
    float* logits = out;            // 30720
    float* kvc    = out + 30720;    // 20480

    init_kernel<<<128, 256, 0, stream>>>(past_hidden, codec_emb, cb0, ws, logits);
    mega_kernel<<<NWG, 256, 0, stream>>>(Wq, Wk, Wv, Wo, qnw, knw, ln1, ln2,
                                         Wg, Wu, Wd, fnw, lmh, ws, logits, kvc);
}

// Round 3
// 637.853 us; speedup vs baseline: 3.2301x; 3.2301x over previous
//
#include <hip/hip_runtime.h>
#include <math.h>

#define EPS 1e-6f
#define NWG 256

// ws float layout:
//   h    @ 0      [2][1024]
//   qkv  @ 2048   5 x [2][3072]   (z: q|k|v blocks of 1024; row1 at +3072)
//   gu   @ 43008  5 x [2][2][4096]  (s, gate/up, f)
//   cnt  @ 126976 (unsigned barrier counter)
#define WS_H    0
#define WS_QKV  2048
#define WS_GU   43008
#define WS_CNT  126976

// coherent (agent-scope, cache-bypassing) load of cross-WG data
__device__ __forceinline__ float cload(const float* p) {
    return __hip_atomic_load(p, __ATOMIC_RELAXED, __HIP_MEMORY_SCOPE_AGENT);
}

// ---------------- init: zero accumulators + barrier + build h ----------------
__global__ void init_kernel(const float* __restrict__ past_hidden,
                            const float* __restrict__ codec_emb,
                            const int* __restrict__ tok,
                            float* __restrict__ ws,
                            float* __restrict__ logits)
{
    int idx = blockIdx.x * blockDim.x + threadIdx.x;
    int stride = gridDim.x * blockDim.x;
    for (int i = idx; i < 30720; i += stride) ws[WS_QKV + i] = 0.f;
    for (int i = idx; i < 81920; i += stride) ws[WS_GU + i] = 0.f;
    for (int i = idx; i < 30720; i += stride) logits[i] = 0.f;
    for (int i = idx; i < 64; i += stride) ((unsigned*)(ws + WS_CNT))[i] = 0u;
    int t = tok[0];
    for (int i = idx; i < 1024; i += stride) {
        ws[i]        = past_hidden[i];
        ws[1024 + i] = codec_emb[(size_t)t * 1024 + i];
    }
}

// ---------------- fence-free grid barrier ----------------
// All cross-WG data moves via device-scope atomics (coherence point), so no
// L2 writeback/invalidate is needed — only completion ordering.
__device__ __forceinline__ void gbar(unsigned* cnt, unsigned target)
{
    asm volatile("s_waitcnt vmcnt(0) lgkmcnt(0)" ::: "memory"); // per-wave: data atomics complete
    __syncthreads();                                             // all waves of WG done
    if (threadIdx.x == 0) {
        __hip_atomic_fetch_add(cnt, 1u, __ATOMIC_RELAXED, __HIP_MEMORY_SCOPE_AGENT);
        while (__hip_atomic_load(cnt, __ATOMIC_RELAXED, __HIP_MEMORY_SCOPE_AGENT) < target)
            __builtin_amdgcn_s_sleep(1);
    }
    __syncthreads();
    asm volatile("" ::: "memory");
}

__device__ __forceinline__ float wave_red64(float v)
{
    for (int o = 32; o >= 1; o >>= 1) v += __shfl_down(v, o, 64);
    return v;
}

// ---------------- rmsnorm prologues (redundant per WG; coherent h reads) ----------------
__device__ __forceinline__ void load_rms2(const float* __restrict__ h,
                                          const float* __restrict__ nw,
                                          float* __restrict__ x0, float* __restrict__ x1,
                                          float* __restrict__ red)
{
    int t = threadIdx.x;
    float ss0 = 0.f, ss1 = 0.f;
    for (int d = t; d < 1024; d += 256) {
        float v0 = cload(h + d), v1 = cload(h + 1024 + d);
        x0[d] = v0; x1[d] = v1;
        ss0 += v0 * v0; ss1 += v1 * v1;
    }
    ss0 = wave_red64(ss0); ss1 = wave_red64(ss1);
    if ((t & 63) == 0) { red[t >> 6] = ss0; red[4 + (t >> 6)] = ss1; }
    __syncthreads();
    float s0 = red[0] + red[1] + red[2] + red[3];
    float s1 = red[4] + red[5] + red[6] + red[7];
    float sc0 = rsqrtf(s0 / 1024.f + EPS);
    float sc1 = rsqrtf(s1 / 1024.f + EPS);
    __syncthreads();
    for (int d = t; d < 1024; d += 256) {
        float w = nw[d];
        x0[d] *= sc0 * w; x1[d] *= sc1 * w;
    }
    __syncthreads();
}

__device__ __forceinline__ void load_rms1(const float* __restrict__ hrow,
                                          const float* __restrict__ nw,
                                          float* __restrict__ x,
                                          float* __restrict__ red)
{
    int t = threadIdx.x;
    float ss = 0.f;
    for (int d = t; d < 1024; d += 256) { float v = cload(hrow + d); x[d] = v; ss += v * v; }
    ss = wave_red64(ss);
    if ((t & 63) == 0) red[t >> 6] = ss;
    __syncthreads();
    float s = red[0] + red[1] + red[2] + red[3];
    float sc = rsqrtf(s / 1024.f + EPS);
    __syncthreads();
    for (int d = t; d < 1024; d += 256) x[d] *= sc * nw[d];
    __syncthreads();
}

// ---------------- GEMV task: 256 cols x 64 K-rows, split-K atomic output ----------------
// Weight loads issue FIRST, then cheap touch loads (1 dword per 128B line) for
// next-phase tiles tA/tB — younger in vmcnt order, so they never block compute.
template <int S>
__device__ __forceinline__ void task_gemm(const float* x0, const float* x1,
                                          const float* __restrict__ Wt, int N,
                                          float* o0, float* o1,
                                          const float* tA, int NA,
                                          const float* tB, int NB,
                                          float* red, float* sink)
{
    const int t = threadIdx.x, lane = t & 63, dp = t >> 6;
    const float* Wp = Wt + (size_t)(dp * 16) * N + (lane << 2);
    float4 w[16];
#pragma unroll
    for (int i = 0; i < 16; ++i)
        w[i] = *reinterpret_cast<const float4*>(Wp + (size_t)i * N);
    asm volatile("" ::: "memory");
    float ta0 = 0.f, ta1 = 0.f, tb0 = 0.f, tb1 = 0.f;
    {
        int li = t * 2, lj = t * 2 + 1;
        if (tA) {
            ta0 = tA[(size_t)(li >> 3) * NA + (li & 7) * 32];
            ta1 = tA[(size_t)(lj >> 3) * NA + (lj & 7) * 32];
        }
        if (tB) {
            tb0 = tB[(size_t)(li >> 3) * NB + (li & 7) * 32];
            tb1 = tB[(size_t)(lj >> 3) * NB + (lj & 7) * 32];
        }
    }
    asm volatile("" ::: "memory");
    const float* xa = x0 + dp * 16;
    const float* xb = (S == 2) ? (x1 + dp * 16) : nullptr;
    float a0 = 0.f, a1 = 0.f, a2 = 0.f, a3 = 0.f;
    float b0 = 0.f, b1 = 0.f, b2 = 0.f, b3 = 0.f;
#pragma unroll
    for (int i = 0; i < 16; ++i) {
        float xv = xa[i];
        a0 += xv * w[i].x; a1 += xv * w[i].y; a2 += xv * w[i].z; a3 += xv * w[i].w;
        if (S == 2) {
            float yv = xb[i];
            b0 += yv * w[i].x; b1 += yv * w[i].y; b2 += yv * w[i].z; b3 += yv * w[i].w;
        }
    }
    __syncthreads();
    red[(dp * S + 0) * 256 + lane * 4 + 0] = a0;
    red[(dp * S + 0) * 256 + lane * 4 + 1] = a1;
    red[(dp * S + 0) * 256 + lane * 4 + 2] = a2;
    red[(dp * S + 0) * 256 + lane * 4 + 3] = a3;
    if (S == 2) {
        red[(dp * S + 1) * 256 + lane * 4 + 0] = b0;
        red[(dp * S + 1) * 256 + lane * 4 + 1] = b1;
        red[(dp * S + 1) * 256 + lane * 4 + 2] = b2;
        red[(dp * S + 1) * 256 + lane * 4 + 3] = b3;
    }
    __syncthreads();
    for (int o = t; o < S * 256; o += 256) {
        int s = o >> 8, col = o & 255;
        float sum = red[(0 * S + s) * 256 + col] + red[(1 * S + s) * 256 + col]
                  + red[(2 * S + s) * 256 + col] + red[(3 * S + s) * 256 + col];
        atomicAdd(((s == 0) ? o0 : o1) + col, sum);
    }
    *sink += ta0 + ta1 + tb0 + tb1;
}

// standalone prefetch for WGs with no task this phase
__device__ __forceinline__ void touch_only(const float* W, int N, float* sink)
{
    int li = threadIdx.x * 2, lj = li + 1;
    float a = W[(size_t)(li >> 3) * N + (li & 7) * 32];
    float b = W[(size_t)(lj >> 3) * N + (lj & 7) * 32];
    *sink += a + b;
}

// ---------------- attention for one head, outputs to LDS, optional kvc ----------------
__device__ void attn_head_lds(const float* __restrict__ qkv,
                              const float* __restrict__ qnw, const float* __restrict__ knw,
                              int head, float* __restrict__ red,
                              float* __restrict__ o0, float* __restrict__ o1,
                              float* __restrict__ kvc)
{
    const int t = threadIdx.x;
    const int d = t & 127;
    const bool act = t < 128;
    float q0 = 0.f, q1 = 0.f, k0 = 0.f, k1 = 0.f, v0 = 0.f, v1 = 0.f, qw = 0.f, kw = 0.f;
    if (act) {
        q0 = cload(qkv + head * 128 + d);         q1 = cload(qkv + 3072 + head * 128 + d);
        k0 = cload(qkv + 1024 + head * 128 + d);  k1 = cload(qkv + 3072 + 1024 + head * 128 + d);
        v0 = cload(qkv + 2048 + head * 128 + d);  v1 = cload(qkv + 3072 + 2048 + head * 128 + d);
        qw = qnw[d]; kw = knw[d];
    }
    auto bred = [&](float val) -> float {
        red[t] = act ? val : 0.f; __syncthreads();
        for (int off = 128; off >= 1; off >>= 1) {
            if (t < off) red[t] += red[t + off];
            __syncthreads();
        }
        float r = red[0]; __syncthreads();
        return r;
    };
    float qs0 = bred(q0 * q0), qs1 = bred(q1 * q1);
    float ks0 = bred(k0 * k0), ks1 = bred(k1 * k1);
    float qsc0 = rsqrtf(qs0 / 128.f + EPS), qsc1 = rsqrtf(qs1 / 128.f + EPS);
    float ksc0 = rsqrtf(ks0 / 128.f + EPS), ksc1 = rsqrtf(ks1 / 128.f + EPS);
    float* qb = red + 256;   // [s][128]
    float* kb = red + 512;
    if (act) {
        qb[d] = q0 * qsc0 * qw; qb[128 + d] = q1 * qsc1 * qw;
        kb[d] = k0 * ksc0 * kw; kb[128 + d] = k1 * ksc1 * kw;
    }
    __syncthreads();
    float qr0 = 0.f, qr1 = 0.f, kr0 = 0.f, kr1 = 0.f;
    if (act) {
        float invf = powf(10000.f, -(float)(d & 63) / 64.f);
        qr0 = qb[d];            // pos 0: angle 0
        kr0 = kb[d];
        float c = cosf(invf), si = sinf(invf);   // pos 1
        float qrot = (d < 64) ? -qb[128 + d + 64] : qb[128 + d - 64];
        float krot = (d < 64) ? -kb[128 + d + 64] : kb[128 + d - 64];
        qr1 = qb[128 + d] * c + qrot * si;
        kr1 = kb[128 + d] * c + krot * si;
        if (kvc) {
            kvc[head * 256 + d]              = kr0;
            kvc[head * 256 + 128 + d]        = kr1;
            kvc[2048 + head * 256 + d]       = v0;
            kvc[2048 + head * 256 + 128 + d] = v1;
        }
    }
    float p00 = bred(qr0 * kr0), p01 = bred(qr0 * kr1);
    float p10 = bred(qr1 * kr0), p11 = bred(qr1 * kr1);
    const float scale = 0.08838834764831845f;
    float s00 = p00 * scale, s01 = p01 * scale - 1e9f;
    float m0 = fmaxf(s00, s01);
    float e0 = expf(s00 - m0), e1 = expf(s01 - m0);
    float in0 = 1.f / (e0 + e1);
    float w00 = e0 * in0, w01 = e1 * in0;
    float s10 = p10 * scale, s11 = p11 * scale;
    float m1 = fmaxf(s10, s11);
    float f0 = expf(s10 - m1), f1 = expf(s11 - m1);
    float in1 = 1.f / (f0 + f1);
    float w10 = f0 * in1, w11 = f1 * in1;
    if (act) {
        o0[d] = w00 * v0 + w01 * v1;
        o1[d] = w10 * v0 + w11 * v1;
    }
    __syncthreads();
}

// ---------------- the persistent mega-kernel ----------------
__global__ __launch_bounds__(256, 1) void mega_kernel(
    const float* __restrict__ Wq, const float* __restrict__ Wk, const float* __restrict__ Wv,
    const float* __restrict__ Wo,
    const float* __restrict__ qnw_all, const float* __restrict__ knw_all,
    const float* __restrict__ ln1_all, const float* __restrict__ ln2_all,
    const float* __restrict__ Wg, const float* __restrict__ Wu, const float* __restrict__ Wd,
    const float* __restrict__ fnw, const float* __restrict__ lmh,
    float* __restrict__ ws, float* __restrict__ logits, float* __restrict__ kvc_all)
{
    __shared__ float xs0[1024];
    __shared__ float xs1[1024];
    __shared__ float red[2048];
    const int wg = blockIdx.x;
    const int t = threadIdx.x;
    unsigned* cnt = (unsigned*)(ws + WS_CNT);
    unsigned target = 0;
    float* h = ws + WS_H;
    float sink = 0.f;

    for (int l = 0; l < 5; ++l) {
        const float* wq_ = Wq + (size_t)l * 1048576;
        const float* wk_ = Wk + (size_t)l * 1048576;
        const float* wv_ = Wv + (size_t)l * 1048576;
        const float* wo_ = Wo + (size_t)l * 1048576;
        const float* wg_ = Wg + (size_t)l * 4194304;
        const float* wu_ = Wu + (size_t)l * 4194304;
        const float* wd_ = Wd + (size_t)l * 4194304;
        float* qkv = ws + WS_QKV + l * 6144;
        float* gu  = ws + WS_GU  + l * 16384;

        // ======== P1: QKV projection (192 tasks) ========
        load_rms2(h, ln1_all + l * 1024, xs0, xs1, red);
        {
            int jb = wg >> 4 & 15, kb = wg & 15;  // generic tile coords for touches
            if (wg < 192) {
                int z = wg >> 6, r = wg & 63, jbq = r >> 4, kbq = r & 15;
                const float* Wz = (z == 0) ? wq_ : ((z == 1) ? wk_ : wv_);
                const float* tch = (wg < 64)
                    ? wo_ + (size_t)(kb * 64) * 1024 + jb * 256          // my O tile
                    : wg_ + (size_t)(kb * 64) * 4096 + jb * 256;         // my gate tile
                int tchN = (wg < 64) ? 1024 : 4096;
                task_gemm<2>(&xs0[kbq * 64], &xs1[kbq * 64],
                             Wz + (size_t)(kbq * 64) * 1024 + jbq * 256, 1024,
                             qkv + z * 1024 + jbq * 256, qkv + 3072 + z * 1024 + jbq * 256,
                             tch, tchN, nullptr, 0, red, &sink);
            } else {
                touch_only(wg_ + (size_t)(kb * 64) * 4096 + jb * 256, 4096, &sink);
            }
        }
        target += NWG; gbar(cnt, target);

        // ======== P2: attention + O projection (64 tasks) ========
        {
            int jb = wg >> 4 & 15, kb = wg & 15;
            if (wg < 64) {
                int head = kb >> 1, half = kb & 1;
                attn_head_lds(qkv, qnw_all + l * 128, knw_all + l * 128, head, red,
                              red + 768, red + 896, nullptr);
                if (t < 64) {
                    xs0[t] = red[768 + half * 64 + t];
                    xs1[t] = red[896 + half * 64 + t];
                }
                __syncthreads();
                task_gemm<2>(&xs0[0], &xs1[0],
                             wo_ + (size_t)(kb * 64) * 1024 + jb * 256, 1024,
                             h + jb * 256, h + 1024 + jb * 256,
                             wg_ + (size_t)(kb * 64) * 4096 + jb * 256, 4096,   // my gate tile
                             wu_ + (size_t)(kb * 64) * 4096 + jb * 256, 4096,   // my up tile
                             red, &sink);
            } else {
                if (wg < 72)  // kv-cache writer WGs
                    attn_head_lds(qkv, qnw_all + l * 128, knw_all + l * 128, wg - 64, red,
                                  red + 768, red + 896, kvc_all + (size_t)(2 * l) * 2048);
                touch_only(wu_ + (size_t)(kb * 64) * 4096 + jb * 256, 4096, &sink);
            }
        }
        target += NWG; gbar(cnt, target);

        // ======== P3: gate + up (256 WGs x 2 tasks) ========
        load_rms2(h, ln2_all + l * 1024, xs0, xs1, red);
        {
            int jb = wg >> 4, kb = wg & 15;
            int jb2 = wg >> 6, kb2 = wg & 63;
            task_gemm<2>(&xs0[kb * 64], &xs1[kb * 64],
                         wg_ + (size_t)(kb * 64) * 4096 + jb * 256, 4096,
                         gu + jb * 256, gu + 8192 + jb * 256,
                         wd_ + (size_t)(kb2 * 64) * 1024 + jb2 * 256, 1024,     // my down tile
                         nullptr, 0, red, &sink);
            task_gemm<2>(&xs0[kb * 64], &xs1[kb * 64],
                         wu_ + (size_t)(kb * 64) * 4096 + jb * 256, 4096,
                         gu + 4096 + jb * 256, gu + 8192 + 4096 + jb * 256,
                         nullptr, 0, nullptr, 0, red, &sink);
        }
        target += NWG; gbar(cnt, target);

        // ======== P4: down proj (256 tasks), silu fused, residual into h ========
        {
            int jb = wg >> 6, kb = wg & 63;
            if (t < 128) {
                int s = t >> 6, f = kb * 64 + (t & 63);
                float g = cload(gu + s * 8192 + f);
                float u = cload(gu + s * 8192 + 4096 + f);
                float a = (g / (1.f + expf(-g))) * u;
                if (s == 0) xs0[t & 63] = a; else xs1[t & 63] = a;
            }
            __syncthreads();
            const float* tch = nullptr; int tchN = 0;
            if (l < 4) {
                if (wg < 192) {
                    int z = wg >> 6, r = wg & 63, jb3 = r >> 4, kb3 = r & 15;
                    const float* nq = (z == 0) ? (Wq + (size_t)(l + 1) * 1048576)
                                   : ((z == 1) ? (Wk + (size_t)(l + 1) * 1048576)
                                               : (Wv + (size_t)(l + 1) * 1048576));
                    tch = nq + (size_t)(kb3 * 64) * 1024 + jb3 * 256; tchN = 1024;
                }
            } else {
                int n = wg >> 7, r = wg & 127, jb3 = r >> 4, kb3 = r & 15;
                tch = lmh + (size_t)n * 2097152 + (size_t)(kb3 * 64) * 2048 + jb3 * 256;
                tchN = 2048;
            }
            task_gemm<2>(&xs0[0], &xs1[0],
                         wd_ + (size_t)(kb * 64) * 1024 + jb * 256, 1024,
                         h + jb * 256, h + 1024 + jb * 256,
                         tch, tchN, nullptr, 0, red, &sink);
        }
        target += NWG; gbar(cnt, target);
    }

    // ======== final norm + lm heads (1920 tasks, self-prefetching rounds) ========
    load_rms1(h + 1024, fnw, xs0, red);
    for (int rr = 0; rr < 8; ++rr) {
        int task = rr * 256 + wg;
        if (task < 1920) {
            int n = task >> 7, r2 = task & 127, jb = r2 >> 4, kb = r2 & 15;
            int tn = task + 256;
            const float* tch = nullptr;
            if (tn < 1920) {
                int n2 = tn >> 7, r3 = tn & 127, jb2 = r3 >> 4, kb2 = r3 & 15;
                tch = lmh + (size_t)n2 * 2097152 + (size_t)(kb2 * 64) * 2048 + jb2 * 256;
            }
            task_gemm<1>(&xs0[kb * 64], nullptr,
                         lmh + (size_t)n * 2097152 + (size_t)(kb * 64) * 2048 + jb * 256, 2048,
                         logits + n * 2048 + jb * 256, nullptr,
                         tch, 2048, nullptr, 0, red, &sink);
        }
    }

    if (sink == -1.2345e38f) atomicAdd(h, 1.0f);   // keep touch loads alive
}

extern "C" void kernel_launch(void* const* d_in, const int* in_sizes, int n_in,
                              void* d_out, int out_size, void* d_ws, size_t ws_size,
                              hipStream_t stream)
{
    const float* past_hidden = (const float*)d_in[0];
    const int*   cb0         = (const int*)d_in[1];
    const float* codec_emb   = (const float*)d_in[2];
    const float* Wq  = (const float*)d_in[3];
    const float* Wk  = (const float*)d_in[4];
    const float* Wv  = (const float*)d_in[5];
    const float* Wo  = (const float*)d_in[6];
    const float* qnw = (const float*)d_in[7];
    const float* knw = (const float*)d_in[8];
    const float* ln1 = (const float*)d_in[9];
    const float* ln2 = (const float*)d_in[10];
    const float* Wg  = (const float*)d_in[11];
    const float* Wu  = (const float*)d_in[12];
    const float* Wd  = (const float*)d_in[13];
    const float* fnw = (const float*)d_in[14];
    const float* lmh = (const float*)d_in[15];

    float* out    = (float*)d_out;
    float* ws     = (float*)d_ws;
    float* logits = out;            // 30720
    float* kvc    = out + 30720;    // 20480

    init_kernel<<<128, 256, 0, stream>>>(past_hidden, codec_emb, cb0, ws, logits);
    mega_kernel<<<NWG, 256, 0, stream>>>(Wq, Wk, Wv, Wo, qnw, knw, ln1, ln2,
                                         Wg, Wu, Wd, fnw, lmh, ws, logits, kvc);
}